// Round 5
// baseline (1779.786 us; speedup 1.0000x reference)
//
#include <hip/hip_runtime.h>

// GATrNet forward, MI355X/gfx950.
// Precision design: logits are computed fp32-exact via f16 hi/lo splitting:
//   hn = hn_hi + hn_lo (two f16 planes), qkv GEMM runs K=1024 with duplicated
//   weight columns; epilogue stores q,k as hi/lo pairs; flash computes
//   S = qhi*khi + qlo*khi + qhi*klo (3 MFMA combos).
// Flash r5: the kernel is serial-latency bound (all pipes <15% busy at 2
// waves/SIMD). Softmax reductions now use DPP row_ror butterflies (VALU,
// ~4cyc) instead of ds_bpermute shuffles (~120cyc); the 128-AGPR alpha
// rescale is branch-skipped when alpha==1 for all rows; S-accumulation is
// split into 4 chains to halve MFMA dependency stalls.

typedef unsigned short u16;
typedef unsigned int u32;
typedef __attribute__((ext_vector_type(4))) float f32x4;
typedef __attribute__((ext_vector_type(8))) _Float16 half8;

__device__ inline u16 f2h(float f) {
  _Float16 h = (_Float16)f;
  return __builtin_bit_cast(u16, h);
}
__device__ inline float h2f(u16 u) { return (float)__builtin_bit_cast(_Float16, u); }

// async global->LDS, 16B per lane. LDS dest = wave-uniform base + lane*16.
__device__ inline void async_cp16(const void* g, void* l) {
  __builtin_amdgcn_global_load_lds((const __attribute__((address_space(1))) u32*)g,
                                   (__attribute__((address_space(3))) u32*)l, 16, 0, 0);
}

__device__ inline f32x4 mfma16(half8 a, half8 b, f32x4 c) {
  return __builtin_amdgcn_mfma_f32_16x16x32_f16(a, b, c, 0, 0, 0);
}

// DPP row_ror move within 16-lane rows (reduction domain = lane&15).
template <int CTRL>
__device__ inline float dpp_mv(float v) {
  int i = __builtin_bit_cast(int, v);
  return __builtin_bit_cast(float, __builtin_amdgcn_update_dpp(i, i, CTRL, 0xf, 0xf, false));
}
// 0x121=ror:1 0x122=ror:2 0x124=ror:4 0x128=ror:8

// INNER_COORDS {0,2,3,4,8,9,10,14} packed 4b each
#define IC_PACK 0xEA984320u

// qkv row layout (width 5120): [q_hi 0,2048) [k_hi 2048,2304) [unused v slot]
// [q_lo 2816,4864) [k_lo 4864,5120)
#define QKV_LD 5120

// ---------------- weight prep ----------------
__global__ void build_wb_enter(const float* __restrict__ we, const float* __restrict__ blade,
                               float* __restrict__ out) {
  int idx = blockIdx.x * 256 + threadIdx.x;
  if (idx >= 32 * 48 * 16) return;
  int j = idx / 768;
  int rem = idx - j * 768;
  int ix = rem >> 4, y = rem & 15;
  int i = ix >> 4, x = ix & 15;
  float acc = 0.f;
#pragma unroll
  for (int bb = 0; bb < 9; ++bb) acc += we[j * 27 + i * 9 + bb] * blade[bb * 256 + x * 16 + y];
  out[idx] = acc;
}

// WqkvT[n][k] f16, K=1024 (k>=512 duplicates k-512 so GEMM computes (hi+lo)*w).
// n<2048 q(inner y, *log2e/16), n<2304 k(inner y), else v(full).
__global__ void build_wqkvT(const float* __restrict__ wq, const float* __restrict__ wk,
                            const float* __restrict__ wv, const float* __restrict__ blade,
                            u16* __restrict__ out) {
  int idx = blockIdx.x * 256 + threadIdx.x;
  if (idx >= 2816 * 1024) return;
  int k = idx & 1023, n = idx >> 10;
  int kk = k & 511;
  int i = kk >> 4, x = kk & 15;
  const float* w;
  int y;
  float scale = 1.0f;
  if (n < 2048) {
    int j = n >> 3;
    y = (IC_PACK >> ((n & 7) * 4)) & 15;
    w = wq + j * 288 + i * 9;
    scale = 0.09016844005556021f;  // (1/16)*log2(e)
  } else if (n < 2304) {
    int m = n - 2048;
    int j = m >> 3;
    y = (IC_PACK >> ((m & 7) * 4)) & 15;
    w = wk + j * 288 + i * 9;
  } else {
    int m = n - 2304;
    int j = m >> 4;
    y = m & 15;
    w = wv + j * 288 + i * 9;
  }
  float acc = 0.f;
#pragma unroll
  for (int bb = 0; bb < 9; ++bb) acc += w[bb] * blade[bb * 256 + x * 16 + y];
  out[idx] = f2h(acc * scale);
}

// WoutT[n][k] f16: n=(j,y)<512, k=(c,x)<4096, w_out[j][c][b]
__global__ void build_woutT(const float* __restrict__ wo, const float* __restrict__ blade,
                            u16* __restrict__ out) {
  int idx = blockIdx.x * 256 + threadIdx.x;
  if (idx >= 512 * 4096) return;
  int k = idx & 4095, n = idx >> 12;
  int j = n >> 4, y = n & 15;
  int c = k >> 4, x = k & 15;
  float acc = 0.f;
#pragma unroll
  for (int bb = 0; bb < 9; ++bb) acc += wo[j * 2304 + c * 9 + bb] * blade[bb * 256 + x * 16 + y];
  out[idx] = f2h(acc);
}

// WfinalT[n][k] f16: n=(j,y)<512, k=(i,x)<512
__global__ void build_wfinalT(const float* __restrict__ wf, const float* __restrict__ blade,
                              u16* __restrict__ out) {
  int idx = blockIdx.x * 256 + threadIdx.x;
  if (idx >= 512 * 512) return;
  int k = idx & 511, n = idx >> 9;
  int j = n >> 4, y = n & 15;
  int i = k >> 4, x = k & 15;
  float acc = 0.f;
#pragma unroll
  for (int bb = 0; bb < 9; ++bb) acc += wf[j * 288 + i * 9 + bb] * blade[bb * 256 + x * 16 + y];
  out[idx] = f2h(acc);
}

// ---------------- enter projection + equi_norm ----------------
// WG = 8 tokens x 32 channels. h fp32 (residual), hn hi/lo f16 planes (row 1024).
__global__ __launch_bounds__(256) void enter_norm(const float* __restrict__ x,
                                                  const float* __restrict__ wb,
                                                  float* __restrict__ h, u16* __restrict__ hn) {
  const int tid = threadIdx.x;
  const int tl = tid >> 5, j = tid & 31;
  const int token = blockIdx.x * 8 + tl;
  const float* xp = x + (size_t)token * 48;
  float xv[48];
#pragma unroll
  for (int q = 0; q < 12; ++q) {
    float4 t = ((const float4*)xp)[q];
    xv[q * 4 + 0] = t.x;
    xv[q * 4 + 1] = t.y;
    xv[q * 4 + 2] = t.z;
    xv[q * 4 + 3] = t.w;
  }
  float acc[16] = {};
  const float* wp = wb + j * 768;
#pragma unroll
  for (int t = 0; t < 48; ++t) {
    const float xs = xv[t];
    const float4* w4 = (const float4*)(wp + t * 16);
#pragma unroll
    for (int u = 0; u < 4; ++u) {
      float4 wv = w4[u];
      acc[u * 4 + 0] += xs * wv.x;
      acc[u * 4 + 1] += xs * wv.y;
      acc[u * 4 + 2] += xs * wv.z;
      acc[u * 4 + 3] += xs * wv.w;
    }
  }
  float ip = acc[0] * acc[0] + acc[2] * acc[2] + acc[3] * acc[3] + acc[4] * acc[4] +
             acc[8] * acc[8] + acc[9] * acc[9] + acc[10] * acc[10] + acc[14] * acc[14];
#pragma unroll
  for (int d = 1; d < 32; d <<= 1) ip += __shfl_xor(ip, d, 64);  // sum over the token's 32 lanes
  const float r = 1.0f / sqrtf(ip * (1.0f / 32.0f));
  float* hp = h + (size_t)token * 512 + j * 16;
#pragma unroll
  for (int u = 0; u < 4; ++u)
    ((float4*)hp)[u] = make_float4(acc[u * 4 + 0], acc[u * 4 + 1], acc[u * 4 + 2], acc[u * 4 + 3]);
  u16 hb[16], lb[16];
#pragma unroll
  for (int y = 0; y < 16; ++y) {
    float sv = acc[y] * r;
    u16 hv = f2h(sv);
    hb[y] = hv;
    lb[y] = f2h(sv - h2f(hv));
  }
  u16* hq = hn + (size_t)token * 1024 + j * 16;
  ((uint4*)hq)[0] = *(const uint4*)&hb[0];
  ((uint4*)hq)[1] = *(const uint4*)&hb[8];
  u16* lq = hq + 512;
  ((uint4*)lq)[0] = *(const uint4*)&lb[0];
  ((uint4*)lq)[1] = *(const uint4*)&lb[8];
}

// ---------------- 128x128 f16 MFMA GEMM, B transposed [N][K] ----------------
// LDS chunk-swizzled (p = c ^ (row&3)) to break 8-way bank conflicts.
// MODE 0: qkv  -> q/k (n<2304) hi+lo into rows of ldc, v (n>=2304) -> vT[b][vd][s]
// MODE 1: outp -> Co f16 = (acc + res)/256
// MODE 2: final-> Cf fp32 = acc*256
template <int MODE>
__global__ __launch_bounds__(256) void gemm_bt(const u16* __restrict__ A,
                                               const u16* __restrict__ BT, int M, int N, int K,
                                               u16* __restrict__ Co, float* __restrict__ Cf,
                                               const float* __restrict__ res,
                                               u16* __restrict__ vT, int ldc) {
  __shared__ u16 ltA[4096];  // [128][32], chunk-swizzled
  __shared__ u16 ltB[4096];
  const int tid = threadIdx.x;
  const int lane = tid & 63;
  const int wid = tid >> 6;
  const int quad = lane >> 4, colc = lane & 15;
  const int m0 = blockIdx.y * 128, n0 = blockIdx.x * 128;
  const int wrow = (wid >> 1) * 64, wcol = (wid & 1) * 64;
  f32x4 acc[4][4] = {};
  const int r0 = tid >> 2;
  const int swk = (((tid & 3) ^ ((tid >> 2) & 3)) << 3);  // swizzled source chunk
  const u16* Ab = A + (size_t)(m0 + r0) * K + swk;
  const u16* Ab2 = Ab + (size_t)64 * K;
  const u16* Bb = BT + (size_t)(n0 + r0) * K + swk;
  const u16* Bb2 = Bb + (size_t)64 * K;
  const int swr = ((colc & 3) << 3);  // read-side swizzle partial
  for (int k0 = 0; k0 < K; k0 += 32) {
    __syncthreads();
    async_cp16(Ab + k0, &ltA[tid * 8]);
    async_cp16(Ab2 + k0, &ltA[2048 + tid * 8]);
    async_cp16(Bb + k0, &ltB[tid * 8]);
    async_cp16(Bb2 + k0, &ltB[2048 + tid * 8]);
    __syncthreads();
    half8 af[4], bfr[4];
#pragma unroll
    for (int i2 = 0; i2 < 4; ++i2)
      af[i2] = *(const half8*)&ltA[(wrow + i2 * 16 + colc) * 32 + ((quad << 3) ^ swr)];
#pragma unroll
    for (int j2 = 0; j2 < 4; ++j2)
      bfr[j2] = *(const half8*)&ltB[(wcol + j2 * 16 + colc) * 32 + ((quad << 3) ^ swr)];
#pragma unroll
    for (int i2 = 0; i2 < 4; ++i2)
#pragma unroll
      for (int j2 = 0; j2 < 4; ++j2) acc[i2][j2] = mfma16(af[i2], bfr[j2], acc[i2][j2]);
  }
#pragma unroll
  for (int i2 = 0; i2 < 4; ++i2) {
#pragma unroll
    for (int j2 = 0; j2 < 4; ++j2) {
      const int mb = m0 + wrow + i2 * 16 + quad * 4;
      const int n = n0 + wcol + j2 * 16 + colc;
#pragma unroll
      for (int rg = 0; rg < 4; ++rg) {
        const int m = mb + rg;
        float v = acc[i2][j2][rg];
        if constexpr (MODE == 0) {
          u16 hv = f2h(v);
          if (n < 2304) {
            Co[(size_t)m * ldc + n] = hv;
            Co[(size_t)m * ldc + 2816 + n] = f2h(v - h2f(hv));
          } else {
            int b = m >> 11, s = m & 2047;
            vT[((size_t)b * 512 + (n - 2304)) * 2048 + s] = hv;
          }
        } else if constexpr (MODE == 1) {
          v += res[(size_t)m * ldc + n];
          Co[(size_t)m * ldc + n] = f2h(v * (1.0f / 256.0f));
        } else {
          Cf[(size_t)m * ldc + n] = v * 256.0f;
        }
      }
    }
  }
}

// ---------------- flash attention ----------------
// grid (qblock=32, head=8, batch=4), 256 thr. Per wave: S (3-combo split-f16)
// for its 16 q-rows, PV for its 128 v-dims over all 64 q-rows (P via LDS).
// One barrier per tile; kt double-buffered; V and k_lo VGPR global loads;
// DPP row_ror softmax reductions; alpha-rescale skipped when alpha==1.
__global__ __launch_bounds__(256, 2) void flash_attn(const u16* __restrict__ qkv,
                                                     const u16* __restrict__ vT,
                                                     u16* __restrict__ out) {
  __shared__ u16 kt[2 * 32 * 256];   // [buf][key][d] swizzled, 2x16KB
  __shared__ u16 pbuf[2 * 64 * 40];  // [buf][qrow][key], padded to 40
  __shared__ float alpha_s[2 * 64];
  __shared__ float l_s[64];
  const int tid = threadIdx.x, lane = tid & 63, wid = tid >> 6;
  const int quad = lane >> 4, colc = lane & 15;
  const int b = blockIdx.z, h = blockIdx.y, qb = blockIdx.x;
  const size_t boff = (size_t)b * 2048 * QKV_LD;
  half8 qh[8], ql[8];
  {
    const u16* qr = qkv + boff + (size_t)(qb * 64 + wid * 16 + colc) * QKV_LD + h * 8;
#pragma unroll
    for (int kb = 0; kb < 8; ++kb) {
      qh[kb] = *(const half8*)(qr + (kb * 4 + quad) * 64);
      ql[kb] = *(const half8*)(qr + 2816 + (kb * 4 + quad) * 64);
    }
  }
  f32x4 oacc[4][8] = {};
  float mrun[4], lrun[4];
#pragma unroll
  for (int rg = 0; rg < 4; ++rg) {
    mrun[rg] = -1e30f;
    lrun[rg] = 0.f;
  }
  const u16* kbase = qkv + boff + 2048;  // k_hi
  const u16* klA = qkv + boff + 4864 + (size_t)colc * QKV_LD + quad * 8;  // k_lo per-lane
  const u16* vbase = vT + (size_t)b * 512 * 2048;
  const u16* vrow = vbase + (size_t)(wid * 128 + colc) * 2048 + quad * 8;  // per-lane V row
  const int ksw = ((colc & 7) << 3);  // kt read swizzle partial
  // staging lane roles (4 cp16 per thread per tile)
  const int skey0 = tid >> 5, sc0 = tid & 31;  // +rr*8 keys
  // prologue: stage kt buf0 for t0=0
#pragma unroll
  for (int rr = 0; rr < 4; ++rr) {
    int key = skey0 + rr * 8;
    async_cp16(kbase + (size_t)key * QKV_LD + ((sc0 ^ (key & 7)) << 3),
               &kt[(skey0 * 32 + sc0 + rr * 256) * 8]);
  }
  __syncthreads();
  for (int it = 0; it < 64; ++it) {
    const int t0 = it * 32;
    const int buf = it & 1;
    const int nbuf = buf ^ 1;
    // issue next tile's kt prefetch (drained by this tile's barrier)
    {
      const int tn = (it == 63) ? t0 : t0 + 32;
#pragma unroll
      for (int rr = 0; rr < 4; ++rr) {
        int key = skey0 + rr * 8;
        async_cp16(kbase + (size_t)(tn + key) * QKV_LD + ((sc0 ^ (key & 7)) << 3),
                   &kt[nbuf * 8192 + (skey0 * 32 + sc0 + rr * 256) * 8]);
      }
    }
    // S [16q x 32k], fp32-exact, 4 accumulation chains for MFMA dep ILP
    f32x4 s0a = {}, s0b = {}, s1a = {}, s1b = {};
    const u16* kl0 = klA + (size_t)t0 * QKV_LD;
    const u16* kl1 = kl0 + (size_t)16 * QKV_LD;
    const u16* ktb = &kt[buf * 8192];
#pragma unroll
    for (int kb = 0; kb < 8; ++kb) {
      half8 khi0 = *(const half8*)&ktb[(0 * 16 + colc) * 256 + (((kb * 4 + quad) << 3) ^ ksw)];
      half8 khi1 = *(const half8*)&ktb[(1 * 16 + colc) * 256 + (((kb * 4 + quad) << 3) ^ ksw)];
      s0a = mfma16(qh[kb], khi0, s0a);
      s0b = mfma16(ql[kb], khi0, s0b);
      s1a = mfma16(qh[kb], khi1, s1a);
      s1b = mfma16(ql[kb], khi1, s1b);
    }
#pragma unroll
    for (int kb = 0; kb < 8; ++kb) {
      half8 klo0 = *(const half8*)(kl0 + kb * 32);
      half8 klo1 = *(const half8*)(kl1 + kb * 32);
      if (kb & 1) {
        s0b = mfma16(qh[kb], klo0, s0b);
        s1b = mfma16(qh[kb], klo1, s1b);
      } else {
        s0a = mfma16(qh[kb], klo0, s0a);
        s1a = mfma16(qh[kb], klo1, s1a);
      }
    }
    f32x4 sfr[2];
    sfr[0] = s0a + s0b;
    sfr[1] = s1a + s1b;
    // online softmax (exp2 domain), DPP row_ror butterflies over colc
    float mx[4];
#pragma unroll
    for (int rg = 0; rg < 4; ++rg) mx[rg] = fmaxf(sfr[0][rg], sfr[1][rg]);
#pragma unroll
    for (int rg = 0; rg < 4; ++rg) mx[rg] = fmaxf(mx[rg], dpp_mv<0x121>(mx[rg]));
#pragma unroll
    for (int rg = 0; rg < 4; ++rg) mx[rg] = fmaxf(mx[rg], dpp_mv<0x122>(mx[rg]));
#pragma unroll
    for (int rg = 0; rg < 4; ++rg) mx[rg] = fmaxf(mx[rg], dpp_mv<0x124>(mx[rg]));
#pragma unroll
    for (int rg = 0; rg < 4; ++rg) mx[rg] = fmaxf(mx[rg], dpp_mv<0x128>(mx[rg]));
    float al[4], pv0[4], pv1[4], rs[4];
#pragma unroll
    for (int rg = 0; rg < 4; ++rg) {
      float mn = fmaxf(mrun[rg], mx[rg]);
      al[rg] = exp2f(mrun[rg] - mn);
      mrun[rg] = mn;
      pv0[rg] = exp2f(sfr[0][rg] - mn);
      pv1[rg] = exp2f(sfr[1][rg] - mn);
      rs[rg] = pv0[rg] + pv1[rg];
    }
#pragma unroll
    for (int rg = 0; rg < 4; ++rg) rs[rg] += dpp_mv<0x121>(rs[rg]);
#pragma unroll
    for (int rg = 0; rg < 4; ++rg) rs[rg] += dpp_mv<0x122>(rs[rg]);
#pragma unroll
    for (int rg = 0; rg < 4; ++rg) rs[rg] += dpp_mv<0x124>(rs[rg]);
#pragma unroll
    for (int rg = 0; rg < 4; ++rg) rs[rg] += dpp_mv<0x128>(rs[rg]);
    const int prow = wid * 16 + quad * 4;
    u16* pb = &pbuf[buf * 2560];
#pragma unroll
    for (int rg = 0; rg < 4; ++rg) {
      lrun[rg] = lrun[rg] * al[rg] + rs[rg];
      pb[(prow + rg) * 40 + colc] = f2h(pv0[rg]);
      pb[(prow + rg) * 40 + 16 + colc] = f2h(pv1[rg]);
    }
    if (colc == 0) {
#pragma unroll
      for (int rg = 0; rg < 4; ++rg) alpha_s[buf * 64 + prow + rg] = al[rg];
    }
    __syncthreads();  // publishes pbuf/alpha; drains next-kt prefetch
    // PV: this wave's 128 v-dims, all 64 q-rows; V frags straight from global
    half8 vf[8];
    {
      const u16* vp = vrow + t0;
#pragma unroll
      for (int vb = 0; vb < 8; ++vb) vf[vb] = *(const half8*)(vp + (size_t)vb * 32768);
    }
    half8 pf[4];
#pragma unroll
    for (int pa = 0; pa < 4; ++pa) pf[pa] = *(const half8*)&pb[(pa * 16 + colc) * 40 + quad * 8];
    float av[4][4];
    float need = 0.f;
#pragma unroll
    for (int pa = 0; pa < 4; ++pa)
#pragma unroll
      for (int rg = 0; rg < 4; ++rg) {
        av[pa][rg] = alpha_s[buf * 64 + pa * 16 + quad * 4 + rg];
        need += __builtin_fabsf(av[pa][rg] - 1.0f);
      }
    if (__any(need != 0.f)) {
#pragma unroll
      for (int pa = 0; pa < 4; ++pa)
#pragma unroll
        for (int vb = 0; vb < 8; ++vb)
#pragma unroll
          for (int rg = 0; rg < 4; ++rg) oacc[pa][vb][rg] *= av[pa][rg];
    }
#pragma unroll
    for (int vb = 0; vb < 8; ++vb)
#pragma unroll
      for (int pa = 0; pa < 4; ++pa) oacc[pa][vb] = mfma16(pf[pa], vf[vb], oacc[pa][vb]);
  }
  {
    const int prow = wid * 16 + quad * 4;
    if (colc == 0) {
#pragma unroll
      for (int rg = 0; rg < 4; ++rg) l_s[prow + rg] = lrun[rg];
    }
  }
  __syncthreads();
  u16* ob = out + ((size_t)b * 2048 + qb * 64) * 4096 + h * 512 + wid * 128;
#pragma unroll
  for (int pa = 0; pa < 4; ++pa) {
    float li[4];
#pragma unroll
    for (int rg = 0; rg < 4; ++rg) li[rg] = 1.0f / l_s[pa * 16 + quad * 4 + rg];
#pragma unroll
    for (int vb = 0; vb < 8; ++vb)
#pragma unroll
      for (int rg = 0; rg < 4; ++rg)
        ob[(size_t)(pa * 16 + quad * 4 + rg) * 4096 + vb * 16 + colc] =
            f2h(oacc[pa][vb][rg] * li[rg]);
  }
}

// ---------------- launcher ----------------
extern "C" void kernel_launch(void* const* d_in, const int* in_sizes, int n_in, void* d_out,
                              int out_size, void* d_ws, size_t ws_size, hipStream_t stream) {
  const float* x = (const float*)d_in[0];
  const float* blade = (const float*)d_in[1];
  const float* w_enter = (const float*)d_in[2];
  const float* w_q = (const float*)d_in[3];
  const float* w_k = (const float*)d_in[4];
  const float* w_v = (const float*)d_in[5];
  const float* w_out = (const float*)d_in[6];
  const float* w_final = (const float*)d_in[7];
  float* out = (float*)d_out;

  char* ws = (char*)d_ws;
  size_t off = 0;
  auto alloc = [&](size_t bytes) {
    void* p = ws + off;
    off = (off + bytes + 255) & ~(size_t)255;
    return p;
  };
  float* wb_enter = (float*)alloc((size_t)32 * 48 * 16 * 4);
  u16* wqkvT = (u16*)alloc((size_t)2816 * 1024 * 2);
  u16* woutT = (u16*)alloc((size_t)512 * 4096 * 2);
  u16* wfinT = (u16*)alloc((size_t)512 * 512 * 2);
  float* hbuf = (float*)alloc((size_t)8192 * 512 * 4);
  u16* hn2 = (u16*)alloc((size_t)8192 * 1024 * 2);
  u16* qkv2 = (u16*)alloc((size_t)8192 * QKV_LD * 2);
  u16* vTb = (u16*)alloc((size_t)4 * 512 * 2048 * 2);
  u16* attno = (u16*)alloc((size_t)8192 * 4096 * 2);
  u16* h2 = (u16*)alloc((size_t)8192 * 512 * 2);

  build_wb_enter<<<96, 256, 0, stream>>>(w_enter, blade, wb_enter);
  build_wqkvT<<<11264, 256, 0, stream>>>(w_q, w_k, w_v, blade, wqkvT);
  build_woutT<<<8192, 256, 0, stream>>>(w_out, blade, woutT);
  build_wfinalT<<<1024, 256, 0, stream>>>(w_final, blade, wfinT);
  enter_norm<<<1024, 256, 0, stream>>>(x, wb_enter, hbuf, hn2);
  gemm_bt<0><<<dim3(22, 64), 256, 0, stream>>>(hn2, wqkvT, 8192, 2816, 1024, qkv2, nullptr,
                                               nullptr, vTb, QKV_LD);
  flash_attn<<<dim3(32, 8, 4), 256, 0, stream>>>(qkv2, vTb, attno);
  gemm_bt<1><<<dim3(4, 64), 256, 0, stream>>>(attno, woutT, 8192, 512, 4096, h2, nullptr, hbuf,
                                              nullptr, 512);
  gemm_bt<2><<<dim3(4, 64), 256, 0, stream>>>(h2, wfinT, 8192, 512, 512, nullptr, out, nullptr,
                                              nullptr, 512);
}

// Round 6
// 954.700 us; speedup vs baseline: 1.8642x; 1.8642x over previous
//
#include <hip/hip_runtime.h>

// GATrNet forward, MI355X/gfx950.
// Precision: logits fp32-exact via f16 hi/lo splitting (hn hi/lo planes,
// K=1024 qkv GEMM, q/k stored hi+lo; S = qhi*khi + qlo*khi + qhi*klo).
// Flash r6: the r3-r5 plateau (~22k cyc/tile-step) was cache-line-transaction
// bound: per-lane k_lo/V loads scattered 64 lines per instruction. Now the
// qkv epilogue writes K_hi/K_lo/V into per-(b,tile) packed 64KB blocks laid
// out as the exact swizzled LDS image; flash stages each tile with a pure
// linear 64KB async copy (512 sequential lines) and has ZERO global loads in
// the hot loop. LDS = 64KB exactly; pbuf/alpha/l_s overlay the lp region
// (dead after S) guarded by a 4-barrier tile sequence.

typedef unsigned short u16;
typedef unsigned int u32;
typedef __attribute__((ext_vector_type(4))) float f32x4;
typedef __attribute__((ext_vector_type(8))) _Float16 half8;

__device__ inline u16 f2h(float f) {
  _Float16 h = (_Float16)f;
  return __builtin_bit_cast(u16, h);
}
__device__ inline float h2f(u16 u) { return (float)__builtin_bit_cast(_Float16, u); }

// async global->LDS, 16B per lane. LDS dest = wave-uniform base + lane*16.
__device__ inline void async_cp16(const void* g, void* l) {
  __builtin_amdgcn_global_load_lds((const __attribute__((address_space(1))) u32*)g,
                                   (__attribute__((address_space(3))) u32*)l, 16, 0, 0);
}

__device__ inline f32x4 mfma16(half8 a, half8 b, f32x4 c) {
  return __builtin_amdgcn_mfma_f32_16x16x32_f16(a, b, c, 0, 0, 0);
}

// DPP row_ror move within 16-lane rows (reduction domain = lane&15).
template <int CTRL>
__device__ inline float dpp_mv(float v) {
  int i = __builtin_bit_cast(int, v);
  return __builtin_bit_cast(float, __builtin_amdgcn_update_dpp(i, i, CTRL, 0xf, 0xf, false));
}

// INNER_COORDS {0,2,3,4,8,9,10,14} packed 4b each
#define IC_PACK 0xEA984320u

// q buffer row: [q_hi 0,2048) [q_lo 2048,4096)
#define Q_LD 4096
// packed KV block per (b,tile): u16 offsets
//   kp [0,8192):      key*256 + (((d>>3)^(key&7))<<3) + (d&7)
//   lp [8192,16384):  same
//   vp [16384,32768): vd*32 + (((key>>3)^(vd&3))<<3) + (key&7)

// ---------------- weight prep ----------------
__global__ void build_wb_enter(const float* __restrict__ we, const float* __restrict__ blade,
                               float* __restrict__ out) {
  int idx = blockIdx.x * 256 + threadIdx.x;
  if (idx >= 32 * 48 * 16) return;
  int j = idx / 768;
  int rem = idx - j * 768;
  int ix = rem >> 4, y = rem & 15;
  int i = ix >> 4, x = ix & 15;
  float acc = 0.f;
#pragma unroll
  for (int bb = 0; bb < 9; ++bb) acc += we[j * 27 + i * 9 + bb] * blade[bb * 256 + x * 16 + y];
  out[idx] = acc;
}

// WqkvT[n][k] f16, K=1024 (k>=512 duplicates k-512 so GEMM computes (hi+lo)*w).
__global__ void build_wqkvT(const float* __restrict__ wq, const float* __restrict__ wk,
                            const float* __restrict__ wv, const float* __restrict__ blade,
                            u16* __restrict__ out) {
  int idx = blockIdx.x * 256 + threadIdx.x;
  if (idx >= 2816 * 1024) return;
  int k = idx & 1023, n = idx >> 10;
  int kk = k & 511;
  int i = kk >> 4, x = kk & 15;
  const float* w;
  int y;
  float scale = 1.0f;
  if (n < 2048) {
    int j = n >> 3;
    y = (IC_PACK >> ((n & 7) * 4)) & 15;
    w = wq + j * 288 + i * 9;
    scale = 0.09016844005556021f;  // (1/16)*log2(e)
  } else if (n < 2304) {
    int m = n - 2048;
    int j = m >> 3;
    y = (IC_PACK >> ((m & 7) * 4)) & 15;
    w = wk + j * 288 + i * 9;
  } else {
    int m = n - 2304;
    int j = m >> 4;
    y = m & 15;
    w = wv + j * 288 + i * 9;
  }
  float acc = 0.f;
#pragma unroll
  for (int bb = 0; bb < 9; ++bb) acc += w[bb] * blade[bb * 256 + x * 16 + y];
  out[idx] = f2h(acc * scale);
}

// WoutT[n][k] f16: n=(j,y)<512, k=(c,x)<4096
__global__ void build_woutT(const float* __restrict__ wo, const float* __restrict__ blade,
                            u16* __restrict__ out) {
  int idx = blockIdx.x * 256 + threadIdx.x;
  if (idx >= 512 * 4096) return;
  int k = idx & 4095, n = idx >> 12;
  int j = n >> 4, y = n & 15;
  int c = k >> 4, x = k & 15;
  float acc = 0.f;
#pragma unroll
  for (int bb = 0; bb < 9; ++bb) acc += wo[j * 2304 + c * 9 + bb] * blade[bb * 256 + x * 16 + y];
  out[idx] = f2h(acc);
}

// WfinalT[n][k] f16: n=(j,y)<512, k=(i,x)<512
__global__ void build_wfinalT(const float* __restrict__ wf, const float* __restrict__ blade,
                              u16* __restrict__ out) {
  int idx = blockIdx.x * 256 + threadIdx.x;
  if (idx >= 512 * 512) return;
  int k = idx & 511, n = idx >> 9;
  int j = n >> 4, y = n & 15;
  int i = k >> 4, x = k & 15;
  float acc = 0.f;
#pragma unroll
  for (int bb = 0; bb < 9; ++bb) acc += wf[j * 288 + i * 9 + bb] * blade[bb * 256 + x * 16 + y];
  out[idx] = f2h(acc);
}

// ---------------- enter projection + equi_norm ----------------
__global__ __launch_bounds__(256) void enter_norm(const float* __restrict__ x,
                                                  const float* __restrict__ wb,
                                                  float* __restrict__ h, u16* __restrict__ hn) {
  const int tid = threadIdx.x;
  const int tl = tid >> 5, j = tid & 31;
  const int token = blockIdx.x * 8 + tl;
  const float* xp = x + (size_t)token * 48;
  float xv[48];
#pragma unroll
  for (int q = 0; q < 12; ++q) {
    float4 t = ((const float4*)xp)[q];
    xv[q * 4 + 0] = t.x;
    xv[q * 4 + 1] = t.y;
    xv[q * 4 + 2] = t.z;
    xv[q * 4 + 3] = t.w;
  }
  float acc[16] = {};
  const float* wp = wb + j * 768;
#pragma unroll
  for (int t = 0; t < 48; ++t) {
    const float xs = xv[t];
    const float4* w4 = (const float4*)(wp + t * 16);
#pragma unroll
    for (int u = 0; u < 4; ++u) {
      float4 wv = w4[u];
      acc[u * 4 + 0] += xs * wv.x;
      acc[u * 4 + 1] += xs * wv.y;
      acc[u * 4 + 2] += xs * wv.z;
      acc[u * 4 + 3] += xs * wv.w;
    }
  }
  float ip = acc[0] * acc[0] + acc[2] * acc[2] + acc[3] * acc[3] + acc[4] * acc[4] +
             acc[8] * acc[8] + acc[9] * acc[9] + acc[10] * acc[10] + acc[14] * acc[14];
#pragma unroll
  for (int d = 1; d < 32; d <<= 1) ip += __shfl_xor(ip, d, 64);
  const float r = 1.0f / sqrtf(ip * (1.0f / 32.0f));
  float* hp = h + (size_t)token * 512 + j * 16;
#pragma unroll
  for (int u = 0; u < 4; ++u)
    ((float4*)hp)[u] = make_float4(acc[u * 4 + 0], acc[u * 4 + 1], acc[u * 4 + 2], acc[u * 4 + 3]);
  u16 hb[16], lb[16];
#pragma unroll
  for (int y = 0; y < 16; ++y) {
    float sv = acc[y] * r;
    u16 hv = f2h(sv);
    hb[y] = hv;
    lb[y] = f2h(sv - h2f(hv));
  }
  u16* hq = hn + (size_t)token * 1024 + j * 16;
  ((uint4*)hq)[0] = *(const uint4*)&hb[0];
  ((uint4*)hq)[1] = *(const uint4*)&hb[8];
  u16* lq = hq + 512;
  ((uint4*)lq)[0] = *(const uint4*)&lb[0];
  ((uint4*)lq)[1] = *(const uint4*)&lb[8];
}

// ---------------- 128x128 f16 MFMA GEMM, B transposed [N][K] ----------------
// MODE 0: qkv -> q hi/lo rows of Co (ldc=4096); k hi/lo + v into packed kvp
//         blocks (LDS-image layout, swizzle baked in)
// MODE 1: outp -> Co f16 = (acc + res)/256
// MODE 2: final-> Cf fp32 = acc*256
template <int MODE>
__global__ __launch_bounds__(256) void gemm_bt(const u16* __restrict__ A,
                                               const u16* __restrict__ BT, int M, int N, int K,
                                               u16* __restrict__ Co, float* __restrict__ Cf,
                                               const float* __restrict__ res,
                                               u16* __restrict__ kvp, int ldc) {
  __shared__ u16 ltA[4096];  // [128][32], chunk-swizzled
  __shared__ u16 ltB[4096];
  const int tid = threadIdx.x;
  const int lane = tid & 63;
  const int wid = tid >> 6;
  const int quad = lane >> 4, colc = lane & 15;
  const int m0 = blockIdx.y * 128, n0 = blockIdx.x * 128;
  const int wrow = (wid >> 1) * 64, wcol = (wid & 1) * 64;
  f32x4 acc[4][4] = {};
  const int r0 = tid >> 2;
  const int swk = (((tid & 3) ^ ((tid >> 2) & 3)) << 3);
  const u16* Ab = A + (size_t)(m0 + r0) * K + swk;
  const u16* Ab2 = Ab + (size_t)64 * K;
  const u16* Bb = BT + (size_t)(n0 + r0) * K + swk;
  const u16* Bb2 = Bb + (size_t)64 * K;
  const int swr = ((colc & 3) << 3);
  for (int k0 = 0; k0 < K; k0 += 32) {
    __syncthreads();
    async_cp16(Ab + k0, &ltA[tid * 8]);
    async_cp16(Ab2 + k0, &ltA[2048 + tid * 8]);
    async_cp16(Bb + k0, &ltB[tid * 8]);
    async_cp16(Bb2 + k0, &ltB[2048 + tid * 8]);
    __syncthreads();
    half8 af[4], bfr[4];
#pragma unroll
    for (int i2 = 0; i2 < 4; ++i2)
      af[i2] = *(const half8*)&ltA[(wrow + i2 * 16 + colc) * 32 + ((quad << 3) ^ swr)];
#pragma unroll
    for (int j2 = 0; j2 < 4; ++j2)
      bfr[j2] = *(const half8*)&ltB[(wcol + j2 * 16 + colc) * 32 + ((quad << 3) ^ swr)];
#pragma unroll
    for (int i2 = 0; i2 < 4; ++i2)
#pragma unroll
      for (int j2 = 0; j2 < 4; ++j2) acc[i2][j2] = mfma16(af[i2], bfr[j2], acc[i2][j2]);
  }
#pragma unroll
  for (int i2 = 0; i2 < 4; ++i2) {
#pragma unroll
    for (int j2 = 0; j2 < 4; ++j2) {
      const int mb = m0 + wrow + i2 * 16 + quad * 4;
      const int n = n0 + wcol + j2 * 16 + colc;
#pragma unroll
      for (int rg = 0; rg < 4; ++rg) {
        const int m = mb + rg;
        float v = acc[i2][j2][rg];
        if constexpr (MODE == 0) {
          u16 hv = f2h(v);
          if (n < 2048) {
            Co[(size_t)m * ldc + n] = hv;
            Co[(size_t)m * ldc + 2048 + n] = f2h(v - h2f(hv));
          } else {
            int bb = m >> 11, s = m & 2047, t = s >> 5, key = s & 31;
            size_t blk = ((size_t)(bb * 64 + t)) << 15;
            if (n < 2304) {
              int d = n - 2048;
              int off = key * 256 + ((((d >> 3) ^ (key & 7)) << 3)) + (d & 7);
              kvp[blk + off] = hv;
              kvp[blk + 8192 + off] = f2h(v - h2f(hv));
            } else {
              int vd = n - 2304;
              kvp[blk + 16384 + vd * 32 + ((((key >> 3) ^ (vd & 3)) << 3)) + (key & 7)] = hv;
            }
          }
        } else if constexpr (MODE == 1) {
          v += res[(size_t)m * ldc + n];
          Co[(size_t)m * ldc + n] = f2h(v * (1.0f / 256.0f));
        } else {
          Cf[(size_t)m * ldc + n] = v * 256.0f;
        }
      }
    }
  }
}

// ---------------- flash attention ----------------
// grid (qblock=32, head=8, batch=4), 256 thr. Per tile: linear 64KB async
// stage of the packed (kp|lp|vp) LDS image; S (48 MFMAs, 4 chains) from
// kp/lp; DPP softmax; pbuf (overlaying lp) publishes P; PV (32 MFMAs) from
// vp. Zero global loads in the loop. 4 barriers/tile guard the overlay.
__global__ __launch_bounds__(256, 2) void flash_attn(const u16* __restrict__ qbuf,
                                                     const u16* __restrict__ kvp,
                                                     u16* __restrict__ out) {
  __shared__ u16 lds[32768];                           // 64KB exactly
  u16* kp = lds;                                       // [32 keys][256 d] swizzled
  u16* lp = lds + 8192;                                // k_lo, same layout
  u16* vp = lds + 16384;                               // [512 vd][32 keys] swizzled
  u16* pbuf = lds + 8192;                              // overlay on lp (dead after S)
  float* alpha_s = (float*)(lds + 8192 + 2560);        // 64 floats
  float* l_s = (float*)(lds + 8192 + 2560 + 128);      // 64 floats
  const int tid = threadIdx.x, lane = tid & 63, wid = tid >> 6;
  const int quad = lane >> 4, colc = lane & 15;
  const int b = blockIdx.z, h = blockIdx.y, qb = blockIdx.x;
  half8 qh[8], ql[8];
  {
    const u16* qr = qbuf + (size_t)(b * 2048 + qb * 64 + wid * 16 + colc) * Q_LD + h * 8;
#pragma unroll
    for (int kb = 0; kb < 8; ++kb) {
      qh[kb] = *(const half8*)(qr + (kb * 4 + quad) * 64);
      ql[kb] = *(const half8*)(qr + 2048 + (kb * 4 + quad) * 64);
    }
  }
  f32x4 oacc[4][8] = {};
  float mrun[4], lrun[4];
#pragma unroll
  for (int rg = 0; rg < 4; ++rg) {
    mrun[rg] = -1e30f;
    lrun[rg] = 0.f;
  }
  const u16* kvb = kvp + ((size_t)(b * 64) << 15);
  const int x0 = colc & 7;
  for (int it = 0; it < 64; ++it) {
    __syncthreads();  // B0: all waves done reading vp/pbuf of previous tile
    {
      const u16* src = kvb + ((size_t)it << 15);
#pragma unroll
      for (int c = 0; c < 16; ++c) {
        int e = c * 256 + tid;
        async_cp16(src + e * 8, &lds[e * 8]);
      }
    }
    __syncthreads();  // B1: stage drained (syncthreads implies vmcnt(0))
    // S [16q x 32k], fp32-exact, 4 accumulation chains
    f32x4 s0a = {}, s0b = {}, s1a = {}, s1b = {};
#pragma unroll
    for (int kb = 0; kb < 8; ++kb) {
      const int sw = (((kb * 4 + quad) ^ x0) << 3);
      half8 khi0 = *(const half8*)&kp[colc * 256 + sw];
      half8 khi1 = *(const half8*)&kp[(16 + colc) * 256 + sw];
      half8 klo0 = *(const half8*)&lp[colc * 256 + sw];
      half8 klo1 = *(const half8*)&lp[(16 + colc) * 256 + sw];
      s0a = mfma16(qh[kb], khi0, s0a);
      s0b = mfma16(ql[kb], khi0, s0b);
      s1a = mfma16(qh[kb], khi1, s1a);
      s1b = mfma16(ql[kb], khi1, s1b);
      if (kb & 1) {
        s0b = mfma16(qh[kb], klo0, s0b);
        s1b = mfma16(qh[kb], klo1, s1b);
      } else {
        s0a = mfma16(qh[kb], klo0, s0a);
        s1a = mfma16(qh[kb], klo1, s1a);
      }
    }
    f32x4 sfr[2];
    sfr[0] = s0a + s0b;
    sfr[1] = s1a + s1b;
    // online softmax (exp2 domain), DPP row_ror butterflies over colc
    float mx[4];
#pragma unroll
    for (int rg = 0; rg < 4; ++rg) mx[rg] = fmaxf(sfr[0][rg], sfr[1][rg]);
#pragma unroll
    for (int rg = 0; rg < 4; ++rg) mx[rg] = fmaxf(mx[rg], dpp_mv<0x121>(mx[rg]));
#pragma unroll
    for (int rg = 0; rg < 4; ++rg) mx[rg] = fmaxf(mx[rg], dpp_mv<0x122>(mx[rg]));
#pragma unroll
    for (int rg = 0; rg < 4; ++rg) mx[rg] = fmaxf(mx[rg], dpp_mv<0x124>(mx[rg]));
#pragma unroll
    for (int rg = 0; rg < 4; ++rg) mx[rg] = fmaxf(mx[rg], dpp_mv<0x128>(mx[rg]));
    float al[4], pv0[4], pv1[4], rs[4];
#pragma unroll
    for (int rg = 0; rg < 4; ++rg) {
      float mn = fmaxf(mrun[rg], mx[rg]);
      al[rg] = exp2f(mrun[rg] - mn);
      mrun[rg] = mn;
      pv0[rg] = exp2f(sfr[0][rg] - mn);
      pv1[rg] = exp2f(sfr[1][rg] - mn);
      rs[rg] = pv0[rg] + pv1[rg];
    }
#pragma unroll
    for (int rg = 0; rg < 4; ++rg) rs[rg] += dpp_mv<0x121>(rs[rg]);
#pragma unroll
    for (int rg = 0; rg < 4; ++rg) rs[rg] += dpp_mv<0x122>(rs[rg]);
#pragma unroll
    for (int rg = 0; rg < 4; ++rg) rs[rg] += dpp_mv<0x124>(rs[rg]);
#pragma unroll
    for (int rg = 0; rg < 4; ++rg) rs[rg] += dpp_mv<0x128>(rs[rg]);
    __syncthreads();  // B2: all S reads of kp/lp done -> lp region reusable
    const int prow = wid * 16 + quad * 4;
#pragma unroll
    for (int rg = 0; rg < 4; ++rg) {
      lrun[rg] = lrun[rg] * al[rg] + rs[rg];
      pbuf[(prow + rg) * 40 + colc] = f2h(pv0[rg]);
      pbuf[(prow + rg) * 40 + 16 + colc] = f2h(pv1[rg]);
    }
    if (colc == 0) {
#pragma unroll
      for (int rg = 0; rg < 4; ++rg) alpha_s[prow + rg] = al[rg];
    }
    __syncthreads();  // B3: pbuf/alpha published
    // PV: this wave's 128 v-dims, all 64 q-rows
    half8 vf[8];
#pragma unroll
    for (int vb = 0; vb < 8; ++vb) {
      const int vd = wid * 128 + vb * 16 + colc;
      vf[vb] = *(const half8*)&vp[vd * 32 + ((quad ^ (vd & 3)) << 3)];
    }
    half8 pf[4];
#pragma unroll
    for (int pa = 0; pa < 4; ++pa)
      pf[pa] = *(const half8*)&pbuf[(pa * 16 + colc) * 40 + quad * 8];
    float av[4][4];
#pragma unroll
    for (int pa = 0; pa < 4; ++pa)
#pragma unroll
      for (int rg = 0; rg < 4; ++rg) av[pa][rg] = alpha_s[pa * 16 + quad * 4 + rg];
#pragma unroll
    for (int pa = 0; pa < 4; ++pa)
#pragma unroll
      for (int vb = 0; vb < 8; ++vb)
#pragma unroll
        for (int rg = 0; rg < 4; ++rg) oacc[pa][vb][rg] *= av[pa][rg];
#pragma unroll
    for (int vb = 0; vb < 8; ++vb)
#pragma unroll
      for (int pa = 0; pa < 4; ++pa) oacc[pa][vb] = mfma16(pf[pa], vf[vb], oacc[pa][vb]);
  }
  {
    const int prow = wid * 16 + quad * 4;
    if (colc == 0) {
#pragma unroll
      for (int rg = 0; rg < 4; ++rg) l_s[prow + rg] = lrun[rg];
    }
  }
  __syncthreads();
  u16* ob = out + ((size_t)b * 2048 + qb * 64) * 4096 + h * 512 + wid * 128;
#pragma unroll
  for (int pa = 0; pa < 4; ++pa) {
    float li[4];
#pragma unroll
    for (int rg = 0; rg < 4; ++rg) li[rg] = 1.0f / l_s[pa * 16 + quad * 4 + rg];
#pragma unroll
    for (int vb = 0; vb < 8; ++vb)
#pragma unroll
      for (int rg = 0; rg < 4; ++rg)
        ob[(size_t)(pa * 16 + quad * 4 + rg) * 4096 + vb * 16 + colc] =
            f2h(oacc[pa][vb][rg] * li[rg]);
  }
}

// ---------------- launcher ----------------
extern "C" void kernel_launch(void* const* d_in, const int* in_sizes, int n_in, void* d_out,
                              int out_size, void* d_ws, size_t ws_size, hipStream_t stream) {
  const float* x = (const float*)d_in[0];
  const float* blade = (const float*)d_in[1];
  const float* w_enter = (const float*)d_in[2];
  const float* w_q = (const float*)d_in[3];
  const float* w_k = (const float*)d_in[4];
  const float* w_v = (const float*)d_in[5];
  const float* w_out = (const float*)d_in[6];
  const float* w_final = (const float*)d_in[7];
  float* out = (float*)d_out;

  char* ws = (char*)d_ws;
  size_t off = 0;
  auto alloc = [&](size_t bytes) {
    void* p = ws + off;
    off = (off + bytes + 255) & ~(size_t)255;
    return p;
  };
  float* wb_enter = (float*)alloc((size_t)32 * 48 * 16 * 4);
  u16* wqkvT = (u16*)alloc((size_t)2816 * 1024 * 2);
  u16* woutT = (u16*)alloc((size_t)512 * 4096 * 2);
  u16* wfinT = (u16*)alloc((size_t)512 * 512 * 2);
  float* hbuf = (float*)alloc((size_t)8192 * 512 * 4);
  u16* hn2 = (u16*)alloc((size_t)8192 * 1024 * 2);
  u16* qbuf = (u16*)alloc((size_t)8192 * Q_LD * 2);
  u16* kvp = (u16*)alloc((size_t)4 * 64 * 32768 * 2);
  u16* attno = (u16*)alloc((size_t)8192 * 4096 * 2);
  u16* h2 = (u16*)alloc((size_t)8192 * 512 * 2);

  build_wb_enter<<<96, 256, 0, stream>>>(w_enter, blade, wb_enter);
  build_wqkvT<<<11264, 256, 0, stream>>>(w_q, w_k, w_v, blade, wqkvT);
  build_woutT<<<8192, 256, 0, stream>>>(w_out, blade, woutT);
  build_wfinalT<<<1024, 256, 0, stream>>>(w_final, blade, wfinT);
  enter_norm<<<1024, 256, 0, stream>>>(x, wb_enter, hbuf, hn2);
  gemm_bt<0><<<dim3(22, 64), 256, 0, stream>>>(hn2, wqkvT, 8192, 2816, 1024, qbuf, nullptr,
                                               nullptr, kvp, Q_LD);
  flash_attn<<<dim3(32, 8, 4), 256, 0, stream>>>(qbuf, kvp, attno);
  gemm_bt<1><<<dim3(4, 64), 256, 0, stream>>>(attno, woutT, 8192, 512, 4096, h2, nullptr, hbuf,
                                              nullptr, 512);
  gemm_bt<2><<<dim3(4, 64), 256, 0, stream>>>(h2, wfinT, 8192, 512, 512, nullptr, out, nullptr,
                                              nullptr, 512);
}